// Round 8
// baseline (258.373 us; speedup 1.0000x reference)
//
#include <hip/hip_runtime.h>

typedef __bf16 bf16;
typedef __bf16 bf16x4 __attribute__((ext_vector_type(4)));
typedef __bf16 bf16x8 __attribute__((ext_vector_type(8)));
typedef float  f32x4  __attribute__((ext_vector_type(4)));
typedef unsigned int uint32;

// ---- ws layout ----
// bf16 region: Q0|Q1|Q2|wfc1|wfc2 ; f32 region: b2,bfc1,bfc2 ; flag ; idx32
#define QR0 339
#define QR1 5825
#define QR2 64
#define OQ0 0
#define OQ1 (OQ0+QR0*256)
#define OQ2 (OQ1+QR1*256)
#define OFC1 (OQ2+QR2*256)
#define OFC2 (OFC1+65536)
#define NBF  (OFC2+256)
#define OFF_F    ((size_t)NBF*2)        // f32: b2(256) bfc1(256) bfc2(1)
#define OFF_FLAG (OFF_F + 520*4)
#define OFF_IDX  (OFF_FLAG + 16)
#define N_IDX    (131072*3)

static __device__ __forceinline__ f32x4 mfma16(bf16x8 a, bf16x8 b, f32x4 c) {
    return __builtin_amdgcn_mfma_f32_16x16x32_bf16(a, b, c, 0, 0, 0);
}

// ---- prep: one kernel, role-split blocks.
// [0,99): build Q from RAW inputs (dtype-branched).
// [99,611): idx -> clamped int32 (vectorized pairs).
// [611,644): wfc1/wfc2 -> bf16 ws; b2/bfc1/bfc2 -> f32 ws; out-dtype flag.
__global__ __launch_bounds__(256, 2)
void prep(const void* __restrict__ e0, const void* __restrict__ e1,
          const void* __restrict__ e2, const void* __restrict__ w1r,
          const void* __restrict__ b1r, const void* __restrict__ w2r,
          const void* __restrict__ b2r, const void* __restrict__ f1r,
          const void* __restrict__ fc1br, const void* __restrict__ f2r,
          const void* __restrict__ fc2br, const void* __restrict__ idxr,
          bf16* __restrict__ wsb, float* __restrict__ wsf,
          int* __restrict__ flagp, int* __restrict__ idx32)
{
    __shared__ alignas(16) bf16 sX[64 * 136];
    __shared__ alignas(16) bf16 sPE[64 * 264];
    __shared__ int sF;

    const int tid = threadIdx.x;
    const int bid = blockIdx.x;
    if (tid == 0) sF = 0;
    __syncthreads();

    if (bid >= 99 && bid < 611) {
        // ---- idx conversion. i64 probe: int64 buffers have all-zero odd words.
        if (((const uint32*)idxr)[tid * 2 + 1] != 0) atomicOr(&sF, 1);
        __syncthreads();
        const bool i64 = (sF == 0);
        const unsigned bid2 = bid - 99;
        for (unsigned g = bid2 * 256u + tid; g < N_IDX / 2; g += 512u * 256u) {
            unsigned k = g * 2;
            long long v0, v1;
            if (i64) {
                uint4 u = ((const uint4*)idxr)[g];
                v0 = (long long)(((unsigned long long)u.y << 32) | u.x);
                v1 = (long long)(((unsigned long long)u.w << 32) | u.z);
            } else {
                uint2 u = ((const uint2*)idxr)[g];
                v0 = (int)u.x; v1 = (int)u.y;
            }
            unsigned m0 = k % 3u, m1 = (k + 1) % 3u;
            long long d0 = (m0 == 0 ? 339 : (m0 == 1 ? 5825 : 64));
            long long d1 = (m1 == 0 ? 339 : (m1 == 1 ? 5825 : 64));
            v0 = v0 < 0 ? 0 : (v0 >= d0 ? d0 - 1 : v0);
            v1 = v1 < 0 ? 0 : (v1 >= d1 ? d1 - 1 : v1);
            uint2 o; o.x = (unsigned)v0; o.y = (unsigned)v1;
            ((uint2*)idx32)[g] = o;
        }
        return;
    }

    // fp32 probe on w1: low 16 bits as bf16 exp>126 impossible for |w1|<=0.37 bf16
    if (tid < 64) {
        uint32 e = (((const uint32*)w1r)[tid] >> 7) & 0xffu;
        if (e > 126u) atomicOr(&sF, 1);
    }
    __syncthreads();
    const bool fp32 = (sF != 0);

    if (bid >= 611) {
        // ---- copy wfc1|wfc2 -> bf16, biases -> f32, flag
        if (bid == 643 && tid == 0) *flagp = fp32 ? 1 : 0;
        const unsigned n4 = (65536 + 256) / 4;  // vec4 over wfc1 then wfc2
        for (unsigned u = (bid - 611) * 256u + tid; u < n4; u += 33u * 256u) {
            unsigned e = u * 4;
            const void* src; unsigned off;
            if (e < 65536) { src = f1r; off = e; }
            else           { src = f2r; off = e - 65536; }
            if (fp32) {
                float4 v = *(const float4*)((const float*)src + off);
                bf16x4 o; o[0]=(bf16)v.x; o[1]=(bf16)v.y; o[2]=(bf16)v.z; o[3]=(bf16)v.w;
                *(bf16x4*)(wsb + OFC1 + e) = o;
            } else {
                *(uint2*)(wsb + OFC1 + e) = *(const uint2*)((const bf16*)src + off);
            }
        }
        if (bid == 643) {
            for (int j = tid; j < 513; j += 256) {
                const void* src; int off;
                if (j < 256)      { src = b2r;   off = j; }
                else if (j < 512) { src = fc1br; off = j - 256; }
                else              { src = fc2br; off = 0; }
                wsf[j] = fp32 ? ((const float*)src)[off] : (float)((const bf16*)src)[off];
            }
        }
        return;
    }

    // ---- build_q: Q_m[i][d] = sum_c relu(<emb_m[i],w1[c]>+b1[c]) * w2[d][c][m]
    const int wave = tid >> 6;
    const int lane = tid & 63;
    const int quad = lane >> 4;
    const int l15  = lane & 15;

    int m, row0, dim; const void* embr; size_t qBase;
    if (bid < 6)       { m = 0; row0 = bid * 64;       dim = 339;  embr = e0; qBase = OQ0; }
    else if (bid < 98) { m = 1; row0 = (bid - 6) * 64; dim = 5825; embr = e1; qBase = OQ1; }
    else               { m = 2; row0 = 0;              dim = 64;   embr = e2; qBase = OQ2; }

    // stage 64 emb rows (clamped) into sX, dtype-branched
    {
        int row = tid >> 2, seg = tid & 3;
        int r = row0 + row; if (r >= dim) r = dim - 1;
        if (fp32) {
            const float* s = (const float*)embr + (size_t)r * 128 + seg * 32;
            #pragma unroll
            for (int u = 0; u < 8; ++u) {
                float4 v = *(const float4*)(s + u * 4);
                bf16x4 o; o[0]=(bf16)v.x; o[1]=(bf16)v.y; o[2]=(bf16)v.z; o[3]=(bf16)v.w;
                *(bf16x4*)(&sX[row * 136 + seg * 32 + u * 4]) = o;
            }
        } else {
            const uint4* s4 = (const uint4*)((const bf16*)embr + (size_t)r * 128 + seg * 32);
            uint4* d4 = (uint4*)(&sX[row * 136 + seg * 32]);
            #pragma unroll
            for (int u = 0; u < 4; ++u) d4[u] = s4[u];
        }
    }
    __syncthreads();

    const f32x4 zero4 = {0.f, 0.f, 0.f, 0.f};

    // PE tile: A=w1 rows c, B=sX rows. D row=c, col=table-row.
    #pragma unroll
    for (int mtl = 0; mtl < 4; ++mtl) {
        int mt = wave * 4 + mtl;
        int c  = mt * 16 + l15;
        bf16x8 aw[4];
        #pragma unroll
        for (int ks = 0; ks < 4; ++ks) {
            if (fp32) {
                const float* s = (const float*)w1r + (size_t)c * 128 + ks * 32 + quad * 8;
                float4 a = *(const float4*)s, b = *(const float4*)(s + 4);
                bf16x8 t;
                t[0]=(bf16)a.x; t[1]=(bf16)a.y; t[2]=(bf16)a.z; t[3]=(bf16)a.w;
                t[4]=(bf16)b.x; t[5]=(bf16)b.y; t[6]=(bf16)b.z; t[7]=(bf16)b.w;
                aw[ks] = t;
            } else {
                aw[ks] = *(const bf16x8*)((const bf16*)w1r + (size_t)c * 128 + ks * 32 + quad * 8);
            }
        }
        float4 bv;
        if (fp32) bv = *(const float4*)((const float*)b1r + mt * 16 + quad * 4);
        else {
            const bf16* s = (const bf16*)b1r + mt * 16 + quad * 4;
            bv.x=(float)s[0]; bv.y=(float)s[1]; bv.z=(float)s[2]; bv.w=(float)s[3];
        }
        #pragma unroll
        for (int nt = 0; nt < 4; ++nt) {
            f32x4 acc = zero4;
            #pragma unroll
            for (int ks = 0; ks < 4; ++ks) {
                bf16x8 xb = *(const bf16x8*)(&sX[(nt * 16 + l15) * 136 + ks * 32 + quad * 8]);
                acc = mfma16(aw[ks], xb, acc);
            }
            bf16x4 hv;
            hv[0] = (bf16)fmaxf(acc[0] + bv.x, 0.f);
            hv[1] = (bf16)fmaxf(acc[1] + bv.y, 0.f);
            hv[2] = (bf16)fmaxf(acc[2] + bv.z, 0.f);
            hv[3] = (bf16)fmaxf(acc[3] + bv.w, 0.f);
            *(bf16x4*)(&sPE[(nt * 16 + l15) * 264 + mt * 16 + quad * 4]) = hv;
        }
    }
    __syncthreads();

    // Q tile: A=sPE rows (table rows), B=w2 rows d (raw, stride-3 scalars). No relu.
    f32x4 acc2[4][4];
    #pragma unroll
    for (int i = 0; i < 4; ++i)
        #pragma unroll
        for (int j = 0; j < 4; ++j) acc2[i][j] = zero4;
    #pragma unroll
    for (int ks = 0; ks < 8; ++ks) {
        bf16x8 af[4], bfr[4];
        #pragma unroll
        for (int mt = 0; mt < 4; ++mt)
            af[mt] = *(const bf16x8*)(&sPE[(mt * 16 + l15) * 264 + ks * 32 + quad * 8]);
        #pragma unroll
        for (int nt = 0; nt < 4; ++nt) {
            int d = wave * 64 + nt * 16 + l15;
            int kb = ks * 32 + quad * 8;
            bf16x8 t;
            if (fp32) {
                const float* s = (const float*)w2r + (size_t)d * 768 + m;
                #pragma unroll
                for (int j = 0; j < 8; ++j) t[j] = (bf16)s[(kb + j) * 3];
            } else {
                const bf16* s = (const bf16*)w2r + (size_t)d * 768 + m;
                #pragma unroll
                for (int j = 0; j < 8; ++j) t[j] = s[(kb + j) * 3];
            }
            bfr[nt] = t;
        }
        #pragma unroll
        for (int mt = 0; mt < 4; ++mt)
            #pragma unroll
            for (int nt = 0; nt < 4; ++nt)
                acc2[mt][nt] = mfma16(af[mt], bfr[nt], acc2[mt][nt]);
    }
    #pragma unroll
    for (int nt = 0; nt < 4; ++nt) {
        int d = wave * 64 + nt * 16 + l15;
        #pragma unroll
        for (int mt = 0; mt < 4; ++mt)
            #pragma unroll
            for (int r = 0; r < 4; ++r) {
                int rl = mt * 16 + quad * 4 + r;
                if (row0 + rl < dim)
                    wsb[qBase + (size_t)(row0 + rl) * 256 + d] = (bf16)acc2[mt][nt][r];
            }
    }
}

// ---- main: LDS-free, barrier-free. Wave w owns batch rows w*16..+15 (M-split).
// A-fragments (h2 = relu(Q0+Q1+Q2+b2)) built directly in registers; B=wfc1 rows e.
__global__ __launch_bounds__(256, 4)
void costco_main(const bf16* __restrict__ wsb, const float* __restrict__ wsf,
                 const int* __restrict__ flagp, const int* __restrict__ idx32,
                 void* __restrict__ out)
{
    const int tid  = threadIdx.x;
    const int wave = tid >> 6;
    const int lane = tid & 63;
    const int quad = lane >> 4;
    const int l15  = lane & 15;
    const int rowA = blockIdx.x * 64 + wave * 16 + l15;   // A-operand row

    const int* ip = idx32 + (size_t)rowA * 3;
    int i0 = ip[0], i1 = ip[1], i2 = ip[2];
    const bf16* q0 = wsb + OQ0 + (size_t)i0 * 256;
    const bf16* q1 = wsb + OQ1 + (size_t)i1 * 256;
    const bf16* q2 = wsb + OQ2 + (size_t)i2 * 256;
    const bf16* wfc1 = wsb + OFC1;
    const float* fb2  = wsf;
    const float* fbc1 = wsf + 256;
    const float  bfc2v = wsf[512];

    const f32x4 zero4 = {0.f, 0.f, 0.f, 0.f};
    f32x4 acc[16];
    #pragma unroll
    for (int i = 0; i < 16; ++i) acc[i] = zero4;

    #pragma unroll 2
    for (int ks = 0; ks < 8; ++ks) {
        const int k0 = ks * 32 + quad * 8;
        bf16x8 a = *(const bf16x8*)(q0 + k0);
        bf16x8 b = *(const bf16x8*)(q1 + k0);
        bf16x8 c = *(const bf16x8*)(q2 + k0);
        float4 bb0 = *(const float4*)(fb2 + k0);
        float4 bb1 = *(const float4*)(fb2 + k0 + 4);
        bf16x8 af;
        af[0] = (bf16)fmaxf((float)a[0]+(float)b[0]+(float)c[0]+bb0.x, 0.f);
        af[1] = (bf16)fmaxf((float)a[1]+(float)b[1]+(float)c[1]+bb0.y, 0.f);
        af[2] = (bf16)fmaxf((float)a[2]+(float)b[2]+(float)c[2]+bb0.z, 0.f);
        af[3] = (bf16)fmaxf((float)a[3]+(float)b[3]+(float)c[3]+bb0.w, 0.f);
        af[4] = (bf16)fmaxf((float)a[4]+(float)b[4]+(float)c[4]+bb1.x, 0.f);
        af[5] = (bf16)fmaxf((float)a[5]+(float)b[5]+(float)c[5]+bb1.y, 0.f);
        af[6] = (bf16)fmaxf((float)a[6]+(float)b[6]+(float)c[6]+bb1.z, 0.f);
        af[7] = (bf16)fmaxf((float)a[7]+(float)b[7]+(float)c[7]+bb1.w, 0.f);
        #pragma unroll
        for (int nt = 0; nt < 16; ++nt) {
            bf16x8 bf = *(const bf16x8*)(wfc1 + (size_t)(nt * 16 + l15) * 256 + k0);
            acc[nt] = mfma16(af, bf, acc[nt]);
        }
    }

    // epilogue: h3 relu + dot(wfc2) + reduce over e (l15 lanes)
    float p[4] = {0.f, 0.f, 0.f, 0.f};
    #pragma unroll
    for (int nt = 0; nt < 16; ++nt) {
        float bc = fbc1[nt * 16 + l15];
        float wv = (float)wsb[OFC2 + nt * 16 + l15];
        #pragma unroll
        for (int r = 0; r < 4; ++r)
            p[r] += fmaxf(acc[nt][r] + bc, 0.f) * wv;
    }
    #pragma unroll
    for (int r = 0; r < 4; ++r) {
        p[r] += __shfl_xor(p[r], 1, 64);
        p[r] += __shfl_xor(p[r], 2, 64);
        p[r] += __shfl_xor(p[r], 4, 64);
        p[r] += __shfl_xor(p[r], 8, 64);
    }
    if (l15 == 0) {
        const int fp32out = *flagp;
        const int orow = blockIdx.x * 64 + wave * 16 + quad * 4;
        #pragma unroll
        for (int r = 0; r < 4; ++r) {
            float v = fmaxf(p[r] + bfc2v, 0.f);
            if (fp32out) ((float*)out)[orow + r] = v;
            else         ((bf16*)out)[orow + r] = (bf16)v;
        }
    }
}

extern "C" void kernel_launch(void* const* d_in, const int* in_sizes, int n_in,
                              void* d_out, int out_size, void* d_ws, size_t ws_size,
                              hipStream_t stream) {
    char* ws = (char*)d_ws;
    bf16*  wsb   = (bf16*)ws;
    float* wsf   = (float*)(ws + OFF_F);
    int*   flagp = (int*)(ws + OFF_FLAG);
    int*   idx32 = (int*)(ws + OFF_IDX);

    hipLaunchKernelGGL(prep, dim3(644), dim3(256), 0, stream,
                       d_in[1], d_in[2], d_in[3], d_in[4], d_in[5], d_in[6],
                       d_in[7], d_in[8], d_in[9], d_in[10], d_in[11], d_in[0],
                       wsb, wsf, flagp, idx32);

    const int B = 131072;
    hipLaunchKernelGGL(costco_main, dim3(B / 64), dim3(256), 0, stream,
                       wsb, wsf, flagp, idx32, d_out);
}

// Round 9
// 168.546 us; speedup vs baseline: 1.5330x; 1.5330x over previous
//
#include <hip/hip_runtime.h>

typedef __bf16 bf16;
typedef __bf16 bf16x4 __attribute__((ext_vector_type(4)));
typedef __bf16 bf16x8 __attribute__((ext_vector_type(8)));
typedef float  f32x4  __attribute__((ext_vector_type(4)));
typedef unsigned int uint32;

// ---- ws layout (bf16 elems): Q0|Q1|Q2|PK(wfc1 packed)|FC2 ; f32: b2,bfc1,bfc2 ; flags
#define QR0 339
#define QR1 5825
#define QR2 64
#define OQ0 0
#define OQ1 (OQ0+QR0*256)
#define OQ2 (OQ1+QR1*256)
#define OPK (OQ2+QR2*256)          // packed wfc1: 16384 frags * 8 = 131072
#define OFC2 (OPK+131072)
#define NBF  (OFC2+256)
#define OFF_F    ((size_t)NBF*2)   // f32: b2(256) bfc1(256) bfc2(1)
#define OFF_FLAG (OFF_F + 520*4)   // int2: {fp32, idx_is_i64}

static __device__ __forceinline__ f32x4 mfma16(bf16x8 a, bf16x8 b, f32x4 c) {
    return __builtin_amdgcn_mfma_f32_16x16x32_bf16(a, b, c, 0, 0, 0);
}

// ---- prep: [0,99) build Q ; [99,163) pack wfc1 ; 163: scalars+flags
__global__ __launch_bounds__(256, 2)
void prep(const void* __restrict__ e0, const void* __restrict__ e1,
          const void* __restrict__ e2, const void* __restrict__ w1r,
          const void* __restrict__ b1r, const void* __restrict__ w2r,
          const void* __restrict__ b2r, const void* __restrict__ f1r,
          const void* __restrict__ fc1br, const void* __restrict__ f2r,
          const void* __restrict__ fc2br, const void* __restrict__ idxr,
          bf16* __restrict__ wsb, float* __restrict__ wsf, int* __restrict__ flagp)
{
    __shared__ alignas(16) bf16 sX[64 * 136];
    __shared__ alignas(16) bf16 sPE[64 * 264];
    __shared__ int sF;

    const int tid = threadIdx.x;
    const int bid = blockIdx.x;
    if (tid == 0) sF = 0;
    __syncthreads();
    // fp32 probe on w1: low 16 bits as bf16 with exp>126 impossible for |w1|<=0.37
    if (tid < 64) {
        uint32 e = (((const uint32*)w1r)[tid] >> 7) & 0xffu;
        if (e > 126u) atomicOr(&sF, 1);
    }
    __syncthreads();
    const bool fp32 = (sF != 0);

    if (bid >= 99 && bid < 163) {
        // pack wfc1 into B-fragment order: one fragment (8 elems) per thread
        int f = (bid - 99) * 256 + tid;          // [0,16384)
        int ks = f >> 10, nt = (f >> 6) & 15, lane = f & 63;
        int e  = nt * 16 + (lane & 15);
        int k  = ks * 32 + (lane >> 4) * 8;
        bf16x8 t;
        if (fp32) {
            const float* s = (const float*)f1r + (size_t)e * 256 + k;
            #pragma unroll
            for (int j = 0; j < 8; ++j) t[j] = (bf16)s[j];
        } else {
            t = *(const bf16x8*)((const bf16*)f1r + (size_t)e * 256 + k);
        }
        *(bf16x8*)(wsb + OPK + (size_t)f * 8) = t;
        return;
    }
    if (bid >= 163) {
        // flags: fp32 + idx dtype (int64 buffers have all-zero odd words)
        if (((const uint32*)idxr)[tid * 2 + 1] != 0) atomicOr(&sF, 2);
        __syncthreads();
        if (tid == 0) { flagp[0] = fp32 ? 1 : 0; flagp[1] = (sF & 2) ? 0 : 1; }
        for (int j = tid; j < 513; j += 256) {
            const void* src; int off;
            if (j < 256)      { src = b2r;   off = j; }
            else if (j < 512) { src = fc1br; off = j - 256; }
            else              { src = fc2br; off = 0; }
            wsf[j] = fp32 ? ((const float*)src)[off] : (float)((const bf16*)src)[off];
        }
        for (int j = tid; j < 256; j += 256)
            wsb[OFC2 + j] = fp32 ? (bf16)((const float*)f2r)[j] : ((const bf16*)f2r)[j];
        return;
    }

    // ---- build_q: Q_m[i][d] = sum_c relu(<emb_m[i],w1[c]>+b1[c]) * w2[d][c][m]
    const int wave = tid >> 6;
    const int lane = tid & 63;
    const int quad = lane >> 4;
    const int l15  = lane & 15;

    int m, row0, dim; const void* embr; size_t qBase;
    if (bid < 6)       { m = 0; row0 = bid * 64;       dim = 339;  embr = e0; qBase = OQ0; }
    else if (bid < 98) { m = 1; row0 = (bid - 6) * 64; dim = 5825; embr = e1; qBase = OQ1; }
    else               { m = 2; row0 = 0;              dim = 64;   embr = e2; qBase = OQ2; }

    {   // stage 64 emb rows (clamped) into sX
        int row = tid >> 2, seg = tid & 3;
        int r = row0 + row; if (r >= dim) r = dim - 1;
        if (fp32) {
            const float* s = (const float*)embr + (size_t)r * 128 + seg * 32;
            #pragma unroll
            for (int u = 0; u < 8; ++u) {
                float4 v = *(const float4*)(s + u * 4);
                bf16x4 o; o[0]=(bf16)v.x; o[1]=(bf16)v.y; o[2]=(bf16)v.z; o[3]=(bf16)v.w;
                *(bf16x4*)(&sX[row * 136 + seg * 32 + u * 4]) = o;
            }
        } else {
            const uint4* s4 = (const uint4*)((const bf16*)embr + (size_t)r * 128 + seg * 32);
            uint4* d4 = (uint4*)(&sX[row * 136 + seg * 32]);
            #pragma unroll
            for (int u = 0; u < 4; ++u) d4[u] = s4[u];
        }
    }
    __syncthreads();

    const f32x4 zero4 = {0.f, 0.f, 0.f, 0.f};

    // PE tile: A=w1 rows c, B=sX rows. D row=c, col=table-row.
    #pragma unroll
    for (int mtl = 0; mtl < 4; ++mtl) {
        int mt = wave * 4 + mtl;
        int c  = mt * 16 + l15;
        bf16x8 aw[4];
        #pragma unroll
        for (int ks = 0; ks < 4; ++ks) {
            if (fp32) {
                const float* s = (const float*)w1r + (size_t)c * 128 + ks * 32 + quad * 8;
                float4 a = *(const float4*)s, b = *(const float4*)(s + 4);
                bf16x8 t;
                t[0]=(bf16)a.x; t[1]=(bf16)a.y; t[2]=(bf16)a.z; t[3]=(bf16)a.w;
                t[4]=(bf16)b.x; t[5]=(bf16)b.y; t[6]=(bf16)b.z; t[7]=(bf16)b.w;
                aw[ks] = t;
            } else {
                aw[ks] = *(const bf16x8*)((const bf16*)w1r + (size_t)c * 128 + ks * 32 + quad * 8);
            }
        }
        float4 bv;
        if (fp32) bv = *(const float4*)((const float*)b1r + mt * 16 + quad * 4);
        else {
            const bf16* s = (const bf16*)b1r + mt * 16 + quad * 4;
            bv.x=(float)s[0]; bv.y=(float)s[1]; bv.z=(float)s[2]; bv.w=(float)s[3];
        }
        #pragma unroll
        for (int nt = 0; nt < 4; ++nt) {
            f32x4 acc = zero4;
            #pragma unroll
            for (int ks = 0; ks < 4; ++ks) {
                bf16x8 xb = *(const bf16x8*)(&sX[(nt * 16 + l15) * 136 + ks * 32 + quad * 8]);
                acc = mfma16(aw[ks], xb, acc);
            }
            bf16x4 hv;
            hv[0] = (bf16)fmaxf(acc[0] + bv.x, 0.f);
            hv[1] = (bf16)fmaxf(acc[1] + bv.y, 0.f);
            hv[2] = (bf16)fmaxf(acc[2] + bv.z, 0.f);
            hv[3] = (bf16)fmaxf(acc[3] + bv.w, 0.f);
            *(bf16x4*)(&sPE[(nt * 16 + l15) * 264 + mt * 16 + quad * 4]) = hv;
        }
    }
    __syncthreads();

    // Q tile: A=sPE rows (table rows), B=w2 rows d (raw, stride-3). No relu.
    f32x4 acc2[4][4];
    #pragma unroll
    for (int i = 0; i < 4; ++i)
        #pragma unroll
        for (int j = 0; j < 4; ++j) acc2[i][j] = zero4;
    #pragma unroll
    for (int ks = 0; ks < 8; ++ks) {
        bf16x8 af[4], bfr[4];
        #pragma unroll
        for (int mt = 0; mt < 4; ++mt)
            af[mt] = *(const bf16x8*)(&sPE[(mt * 16 + l15) * 264 + ks * 32 + quad * 8]);
        #pragma unroll
        for (int nt = 0; nt < 4; ++nt) {
            int d = wave * 64 + nt * 16 + l15;
            int kb = ks * 32 + quad * 8;
            bf16x8 t;
            if (fp32) {
                const float* s = (const float*)w2r + (size_t)d * 768 + m;
                #pragma unroll
                for (int j = 0; j < 8; ++j) t[j] = (bf16)s[(kb + j) * 3];
            } else {
                const bf16* s = (const bf16*)w2r + (size_t)d * 768 + m;
                #pragma unroll
                for (int j = 0; j < 8; ++j) t[j] = s[(kb + j) * 3];
            }
            bfr[nt] = t;
        }
        #pragma unroll
        for (int mt = 0; mt < 4; ++mt)
            #pragma unroll
            for (int nt = 0; nt < 4; ++nt)
                acc2[mt][nt] = mfma16(af[mt], bfr[nt], acc2[mt][nt]);
    }
    #pragma unroll
    for (int nt = 0; nt < 4; ++nt) {
        int d = wave * 64 + nt * 16 + l15;
        #pragma unroll
        for (int mt = 0; mt < 4; ++mt)
            #pragma unroll
            for (int r = 0; r < 4; ++r) {
                int rl = mt * 16 + quad * 4 + r;
                if (row0 + rl < dim)
                    wsb[qBase + (size_t)(row0 + rl) * 256 + d] = (bf16)acc2[mt][nt][r];
            }
    }
}

// ---- main: LDS-free. Wave handles 32 batch rows (2 rowsets of 16) sharing each
// packed-wfc1 B-fragment. Coalesced 1KB B-loads; raw idx with inline clamp.
__global__ __launch_bounds__(256, 2)
void costco_main(const bf16* __restrict__ wsb, const float* __restrict__ wsf,
                 const int* __restrict__ flagp, const void* __restrict__ idxr,
                 void* __restrict__ out)
{
    const int tid  = threadIdx.x;
    const int wave = tid >> 6;
    const int lane = tid & 63;
    const int quad = lane >> 4;
    const int l15  = lane & 15;
    const int fp32out = flagp[0];
    const int idx64   = flagp[1];

    const bf16* wpk  = wsb + OPK;
    const float* fb2  = wsf;
    const float* fbc1 = wsf + 256;
    const float  bfc2v = wsf[512];

    // two rowsets per wave: rows base+l15 and base+64+l15
    const int rbase = blockIdx.x * 128 + wave * 16;
    const bf16* q[2][3];
    #pragma unroll
    for (int s = 0; s < 2; ++s) {
        size_t row = (size_t)(rbase + s * 64 + l15);
        long long i0, i1, i2;
        if (idx64) {
            const long long* p = (const long long*)idxr + row * 3;
            i0 = p[0]; i1 = p[1]; i2 = p[2];
        } else {
            const int* p = (const int*)idxr + row * 3;
            i0 = p[0]; i1 = p[1]; i2 = p[2];
        }
        i0 = i0 < 0 ? 0 : (i0 >= 339  ? 338  : i0);
        i1 = i1 < 0 ? 0 : (i1 >= 5825 ? 5824 : i1);
        i2 = i2 < 0 ? 0 : (i2 >= 64   ? 63   : i2);
        q[s][0] = wsb + OQ0 + (size_t)i0 * 256;
        q[s][1] = wsb + OQ1 + (size_t)i1 * 256;
        q[s][2] = wsb + OQ2 + (size_t)i2 * 256;
    }

    const f32x4 zero4 = {0.f, 0.f, 0.f, 0.f};
    f32x4 acc0[16], acc1[16];
    #pragma unroll
    for (int i = 0; i < 16; ++i) { acc0[i] = zero4; acc1[i] = zero4; }

    #pragma unroll 1
    for (int ks = 0; ks < 8; ++ks) {
        const int k0 = ks * 32 + quad * 8;
        float4 bb0 = *(const float4*)(fb2 + k0);
        float4 bb1 = *(const float4*)(fb2 + k0 + 4);
        bf16x8 af[2];
        #pragma unroll
        for (int s = 0; s < 2; ++s) {
            bf16x8 a = *(const bf16x8*)(q[s][0] + k0);
            bf16x8 b = *(const bf16x8*)(q[s][1] + k0);
            bf16x8 c = *(const bf16x8*)(q[s][2] + k0);
            bf16x8 t;
            t[0] = (bf16)fmaxf((float)a[0]+(float)b[0]+(float)c[0]+bb0.x, 0.f);
            t[1] = (bf16)fmaxf((float)a[1]+(float)b[1]+(float)c[1]+bb0.y, 0.f);
            t[2] = (bf16)fmaxf((float)a[2]+(float)b[2]+(float)c[2]+bb0.z, 0.f);
            t[3] = (bf16)fmaxf((float)a[3]+(float)b[3]+(float)c[3]+bb0.w, 0.f);
            t[4] = (bf16)fmaxf((float)a[4]+(float)b[4]+(float)c[4]+bb1.x, 0.f);
            t[5] = (bf16)fmaxf((float)a[5]+(float)b[5]+(float)c[5]+bb1.y, 0.f);
            t[6] = (bf16)fmaxf((float)a[6]+(float)b[6]+(float)c[6]+bb1.z, 0.f);
            t[7] = (bf16)fmaxf((float)a[7]+(float)b[7]+(float)c[7]+bb1.w, 0.f);
            af[s] = t;
        }
        const bf16* pk = wpk + ((size_t)ks * 1024 + lane) * 8;
        #pragma unroll
        for (int nt = 0; nt < 16; ++nt) {
            bf16x8 bf = *(const bf16x8*)(pk + (size_t)nt * 512);
            acc0[nt] = mfma16(af[0], bf, acc0[nt]);
            acc1[nt] = mfma16(af[1], bf, acc1[nt]);
        }
    }

    // epilogue per rowset: h3 relu + dot(wfc2) + l15-reduce + store
    #pragma unroll
    for (int s = 0; s < 2; ++s) {
        float p[4] = {0.f, 0.f, 0.f, 0.f};
        #pragma unroll
        for (int nt = 0; nt < 16; ++nt) {
            float bc = fbc1[nt * 16 + l15];
            float wv = (float)wsb[OFC2 + nt * 16 + l15];
            const f32x4* ac = s ? acc1 : acc0;
            #pragma unroll
            for (int r = 0; r < 4; ++r)
                p[r] += fmaxf(ac[nt][r] + bc, 0.f) * wv;
        }
        #pragma unroll
        for (int r = 0; r < 4; ++r) {
            p[r] += __shfl_xor(p[r], 1, 64);
            p[r] += __shfl_xor(p[r], 2, 64);
            p[r] += __shfl_xor(p[r], 4, 64);
            p[r] += __shfl_xor(p[r], 8, 64);
        }
        if (l15 == 0) {
            const int orow = rbase + s * 64 + quad * 4;
            #pragma unroll
            for (int r = 0; r < 4; ++r) {
                float v = fmaxf(p[r] + bfc2v, 0.f);
                if (fp32out) ((float*)out)[orow + r] = v;
                else         ((bf16*)out)[orow + r] = (bf16)v;
            }
        }
    }
}

extern "C" void kernel_launch(void* const* d_in, const int* in_sizes, int n_in,
                              void* d_out, int out_size, void* d_ws, size_t ws_size,
                              hipStream_t stream) {
    char* ws = (char*)d_ws;
    bf16*  wsb   = (bf16*)ws;
    float* wsf   = (float*)(ws + OFF_F);
    int*   flagp = (int*)(ws + OFF_FLAG);

    hipLaunchKernelGGL(prep, dim3(164), dim3(256), 0, stream,
                       d_in[1], d_in[2], d_in[3], d_in[4], d_in[5], d_in[6],
                       d_in[7], d_in[8], d_in[9], d_in[10], d_in[11], d_in[0],
                       wsb, wsf, flagp);

    const int B = 131072;
    hipLaunchKernelGGL(costco_main, dim3(B / 128), dim3(256), 0, stream,
                       wsb, wsf, flagp, d_in[0], d_out);
}